// Round 4
// baseline (291.973 us; speedup 1.0000x reference)
//
#include <hip/hip_runtime.h>
#include <hip/hip_bf16.h>

#define NEG (-1e30f)
#define M_ROWS 8000   // B*T = 16*500
#define N_COLS 5000   // V
#define K_DIM  256    // D
#define T_LEN  500
#define T_PAD  512    // lgT inner stride (t)
#define B_SZ   16
#define L_LAB  50
#define DP_STR  516   // k_dp LDS row stride (dwords)
#define LOG2E   1.4426950408889634f
#define LN2     0.6931471805599453f

typedef _Float16 half8  __attribute__((ext_vector_type(8)));
typedef _Float16 half4v __attribute__((ext_vector_type(4)));
typedef float    floatx4 __attribute__((ext_vector_type(4)));

#define AS_G(p) ((const __attribute__((address_space(1))) void*)(const void*)(p))
#define AS_L(p) ((__attribute__((address_space(3))) void*)(void*)(p))

__device__ __forceinline__ float fexp2(float x) {
#if defined(__has_builtin)
#if __has_builtin(__builtin_amdgcn_exp2f)
  return __builtin_amdgcn_exp2f(x);
#else
  return __expf(x * LN2);
#endif
#else
  return __expf(x * LN2);
#endif
}
__device__ __forceinline__ float flog2(float x) {
#if defined(__has_builtin)
#if __has_builtin(__builtin_amdgcn_logf)
  return __builtin_amdgcn_logf(x);
#else
  return __logf(x) * LOG2E;
#endif
#else
  return __logf(x) * LOG2E;
#endif
}
__device__ __forceinline__ float wave_shr1(float x, float fill) {
#if defined(__has_builtin)
#if __has_builtin(__builtin_amdgcn_update_dpp)
  int r = __builtin_amdgcn_update_dpp(__float_as_int(fill), __float_as_int(x),
                                      0x138 /*wave_shr:1*/, 0xf, 0xf, false);
  return __int_as_float(r);
#else
  return __shfl_up(x, 1);
#endif
#else
  return __shfl_up(x, 1);
#endif
}

// ---------------- fused fp32->fp16 (enc + W) + out zeroing ------------------------
__global__ void k_f2h2(const float* __restrict__ enc, const float* __restrict__ W,
                       _Float16* __restrict__ ench, _Float16* __restrict__ wh,
                       float* z) {
  int i = blockIdx.x * blockDim.x + threadIdx.x;
  if (i == 0) z[0] = 0.0f;
  if (i < 512000) {
    float4 v = ((const float4*)enc)[i];
    half4v o = {(_Float16)v.x, (_Float16)v.y, (_Float16)v.z, (_Float16)v.w};
    ((half4v*)ench)[i] = o;
  } else {
    int k = i - 512000;
    if (k < 320000) {
      float4 v = ((const float4*)W)[k];
      half4v o = {(_Float16)v.x, (_Float16)v.y, (_Float16)v.z, (_Float16)v.w};
      ((half4v*)wh)[k] = o;
    }
  }
}

// ---------------- MFMA GEMM + fused lse partials + label-logit scatter ------------
// Staging: global_load_lds width-16, XOR-swizzled LDS layout:
//   phys f16 addr of (row r, 16B-chunk kc) = r*64 + ((kc ^ (r&7))<<3)
// -> every 16-lane ds_read_b128 phase hits all 32 banks exactly 2x (wave64 floor).
__global__ __launch_bounds__(256) void k_gemm_lse(
    const _Float16* __restrict__ A, const _Float16* __restrict__ Bm,
    const float* __restrict__ bias, const int* __restrict__ y,
    float* __restrict__ pmax, float* __restrict__ psum, float* __restrict__ lgT) {
  __shared__ _Float16 As[128 * 64];   // 16 KB
  __shared__ _Float16 Bs[128 * 64];   // 16 KB

  const int tid = threadIdx.x;
  const int lane = tid & 63;
  const int wid = tid >> 6;
  const int wave_m = wid & 1, wave_n = wid >> 1;   // 2x2 waves of 64x64
  const int l15 = lane & 15, quad = lane >> 4;
  const int m0 = blockIdx.y * 128, n0 = blockIdx.x * 128;

  // per-lane staging source: lane l covers (row = base_r + (l>>3), chunk kc = (l&7)^(l>>3))
  const int dr = lane >> 3;
  const int kc = (lane & 7) ^ dr;
  int arow[4], brow[4];
  #pragma unroll
  for (int g = 0; g < 4; ++g) {
    int r = wid * 32 + g * 8 + dr;
    int ga = m0 + r; if (ga > M_ROWS - 1) ga = M_ROWS - 1;
    int gb = n0 + r; if (gb > N_COLS - 1) gb = N_COLS - 1;
    arow[g] = ga; brow[g] = gb;
  }

  floatx4 acc[4][4];
  floatx4 zz = {0.f, 0.f, 0.f, 0.f};
  #pragma unroll
  for (int mi = 0; mi < 4; ++mi)
    #pragma unroll
    for (int ni = 0; ni < 4; ++ni) acc[mi][ni] = zz;

  for (int kk = 0; kk < K_DIM; kk += 64) {
    #pragma unroll
    for (int g = 0; g < 4; ++g) {
      __builtin_amdgcn_global_load_lds(
          AS_G(A + (size_t)arow[g] * K_DIM + kk + kc * 8),
          AS_L(As + (wid * 32 + g * 8) * 64), 16, 0, 0);
      __builtin_amdgcn_global_load_lds(
          AS_G(Bm + (size_t)brow[g] * K_DIM + kk + kc * 8),
          AS_L(Bs + (wid * 32 + g * 8) * 64), 16, 0, 0);
    }
    __syncthreads();   // compiler drains vmcnt before s_barrier
    #pragma unroll
    for (int ko4 = 0; ko4 < 8; ko4 += 4) {   // k-chunk offset 0,4 (= f16 0,32)
      half8 af[4], bf[4];
      #pragma unroll
      for (int mi = 0; mi < 4; ++mi) {
        int r = wave_m * 64 + mi * 16 + l15;
        af[mi] = *(const half8*)(As + r * 64 + (((quad + ko4) ^ (r & 7)) << 3));
      }
      #pragma unroll
      for (int ni = 0; ni < 4; ++ni) {
        int r = wave_n * 64 + ni * 16 + l15;
        bf[ni] = *(const half8*)(Bs + r * 64 + (((quad + ko4) ^ (r & 7)) << 3));
      }
      #pragma unroll
      for (int mi = 0; mi < 4; ++mi)
        #pragma unroll
        for (int ni = 0; ni < 4; ++ni)
          acc[mi][ni] = __builtin_amdgcn_mfma_f32_16x16x32_f16(af[mi], bf[ni], acc[mi][ni], 0, 0, 0);
    }
    __syncthreads();
  }

  // ---- epilogue 1: bias + column masks ----
  float bvv[4]; bool cok[4];
  #pragma unroll
  for (int ni = 0; ni < 4; ++ni) {
    int col = n0 + wave_n * 64 + ni * 16 + l15;
    cok[ni] = (col < N_COLS);
    bvv[ni] = cok[ni] ? bias[col] : 0.f;
  }

  // ---- epilogue 2: scatter label logits (j=0 blank, j=1..50 = y[b][j-1]) ----
  // C/D layout: col = lane&15, row = quad*4 + reg.
  const int nbase = n0 + wave_n * 64;
  const int mbase = m0 + wave_m * 64;
  int b_lo = mbase / T_LEN;
  int b_hi = (mbase + 63) / T_LEN;
  if (b_hi > B_SZ - 1) b_hi = B_SZ - 1;
  for (int b = b_lo; b <= b_hi; ++b) {
    #pragma unroll 1
    for (int j = 0; j < 51; ++j) {
      int v = (j == 0) ? 0 : y[b * L_LAB + j - 1];
      int dv = v - nbase;
      if (dv < 0 || dv >= 64) continue;       // wave-uniform skip
      if ((dv & 15) != l15) continue;         // 4 lanes (quad 0..3) continue
      int ni = dv >> 4;
      float bb = bvv[0];
      bb = (ni == 1) ? bvv[1] : bb;
      bb = (ni == 2) ? bvv[2] : bb;
      bb = (ni == 3) ? bvv[3] : bb;
      #pragma unroll
      for (int mi = 0; mi < 4; ++mi) {
        #pragma unroll
        for (int r = 0; r < 4; ++r) {
          float val = acc[mi][0][r];
          val = (ni == 1) ? acc[mi][1][r] : val;
          val = (ni == 2) ? acc[mi][2][r] : val;
          val = (ni == 3) ? acc[mi][3][r] : val;
          int grow = mbase + mi * 16 + quad * 4 + r;
          int t = grow - b * T_LEN;
          if (t >= 0 && t < T_LEN && grow < M_ROWS)
            lgT[((size_t)b * 51 + j) * T_PAD + t] = val + bb;
        }
      }
    }
  }

  // ---- epilogue 3: row-wise (max, sumexp) partials over this wave's 64 cols ----
  const int cchunk = blockIdx.x * 2 + wave_n;
  #pragma unroll
  for (int mi = 0; mi < 4; ++mi) {
    #pragma unroll
    for (int r = 0; r < 4; ++r) {
      int grow = mbase + mi * 16 + quad * 4 + r;
      float v0 = cok[0] ? acc[mi][0][r] + bvv[0] : NEG;
      float v1 = cok[1] ? acc[mi][1][r] + bvv[1] : NEG;
      float v2 = cok[2] ? acc[mi][2][r] + bvv[2] : NEG;
      float v3 = cok[3] ? acc[mi][3][r] + bvv[3] : NEG;
      float mx = fmaxf(fmaxf(v0, v1), fmaxf(v2, v3));
      #pragma unroll
      for (int d = 1; d < 16; d <<= 1) mx = fmaxf(mx, __shfl_xor(mx, d));
      float se = __expf(v0 - mx) + __expf(v1 - mx) + __expf(v2 - mx) + __expf(v3 - mx);
      #pragma unroll
      for (int d = 1; d < 16; d <<= 1) se += __shfl_xor(se, d);
      if (l15 == 0 && grow < M_ROWS) {
        pmax[(size_t)grow * 80 + cchunk] = mx;
        psum[(size_t)grow * 80 + cchunk] = se;
      }
    }
  }
}

// ---------------- CTC forward DP + fused lse reduction ----------------------------
// One block (256 thr) per batch element. All waves stage lgT[b] (51x500 used) into
// LDS; then wave 0 runs the serial DP (base-2 domain) while waves 1-3 combine
// pmax/psum -> sum_t lse[b,t].
__global__ __launch_bounds__(256) void k_dp(
    const float* __restrict__ lgT, const float* __restrict__ pmax,
    const float* __restrict__ psum, const int* __restrict__ enc_lens,
    const int* __restrict__ y, const int* __restrict__ y_lens,
    float* __restrict__ out) {
  __shared__ float sA[51 * DP_STR];   // ~105 KB
  __shared__ float sRed[4];
  const int b = blockIdx.x, tid = threadIdx.x;
  const int Tb = enc_lens[b], yl = y_lens[b];

  const float* g = lgT + (size_t)b * 51 * T_PAD;
  #pragma unroll
  for (int k = 0; k < 26; ++k) {
    int idx = tid + k * 256;
    if (idx < 51 * 128) {
      int row = idx >> 7, c4 = (idx & 127) << 2;
      float4 v = *(const float4*)(g + (size_t)row * T_PAD + c4);
      float4 s = {v.x * LOG2E, v.y * LOG2E, v.z * LOG2E, v.w * LOG2E};
      *(float4*)(sA + row * DP_STR + c4) = s;
    }
  }
  __syncthreads();

  if (tid < 64) {
    const int i = tid;
    const int jj = (i + 1 < 50) ? (i + 1) : 50;
    const float* bl = sA;
    const float* ow = sA + jj * DP_STR;
    const bool v0 = (i <= 50), v1 = (i <= 49);
    const bool lane0 = (i == 0);
    const bool skip1 = (i >= 1 && i <= 49) && (y[b * L_LAB + i] != y[b * L_LAB + i - 1]);

    float4 A0 = *(const float4*)(bl + 0),  A1 = *(const float4*)(ow + 0);
    float4 B0 = *(const float4*)(bl + 4),  B1 = *(const float4*)(ow + 4);
    float4 C0 = *(const float4*)(bl + 8),  C1 = *(const float4*)(ow + 8);
    float4 D0 = *(const float4*)(bl + 12), D1 = *(const float4*)(ow + 12);
    const float4 n4 = {NEG, NEG, NEG, NEG};
    if (!v1) { A1 = n4; B1 = n4; C1 = n4; D1 = n4; }

    float a0 = lane0 ? A0.x : NEG;
    float a1 = lane0 ? A1.x : NEG;

    auto step = [&](float l0r, float l1) {
      float l0 = v0 ? l0r : NEG;
      float p1 = wave_shr1(a1, NEG);
      p1 = lane0 ? NEG : p1;
      float th = skip1 ? p1 : NEG;
      float m0 = fmaxf(a0, p1);
      float na0 = m0 + flog2(fexp2(a0 - m0) + fexp2(p1 - m0)) + l0;
      float m1 = fmaxf(fmaxf(a1, a0), th);
      float na1 = m1 + flog2(fexp2(a1 - m1) + fexp2(a0 - m1) + fexp2(th - m1)) + l1;
      a0 = na0; a1 = na1;
    };

    step(A0.y, A1.y);
    step(A0.z, A1.z);
    step(A0.w, A1.w);

    float4 c0 = B0, c1 = B1, n0v = C0, n1v = C1, nn0 = D0, nn1 = D1;
    int t = 4;
    while (t + 4 <= Tb) {
      float4 p0 = *(const float4*)(bl + t + 12);   // max 511 < 512 in-bounds
      float4 p1v = *(const float4*)(ow + t + 12);
      if (!v1) p1v = n4;
      step(c0.x, c1.x);
      step(c0.y, c1.y);
      step(c0.z, c1.z);
      step(c0.w, c1.w);
      c0 = n0v; c1 = n1v; n0v = nn0; n1v = nn1; nn0 = p0; nn1 = p1v;
      t += 4;
    }
    if (t < Tb) { step(c0.x, c1.x); ++t; }
    if (t < Tb) { step(c0.y, c1.y); ++t; }
    if (t < Tb) { step(c0.z, c1.z); ++t; }

    float ea = __shfl(a0, yl);       // s = 2*yl
    float eb = __shfl(a1, yl - 1);   // s = 2*yl-1
    if (lane0) {
      float m = fmaxf(ea, eb);
      float fin2 = m + flog2(fexp2(ea - m) + fexp2(eb - m));
      sRed[0] = LN2 * fin2;          // natural-log domain
    }
  } else {
    // waves 1..3: sum_t lse(b,t) from the 80-chunk partials
    const int w = (tid >> 6) - 1;    // 0..2
    const int lane = tid & 63;
    float sl = 0.f;
    for (int t = w; t < Tb; t += 3) {
      const size_t row = (size_t)(b * T_LEN + t) * 80;
      float m0 = pmax[row + lane];
      float s0 = psum[row + lane];
      float m1 = NEG, s1 = 0.f;
      if (lane < 16) { m1 = pmax[row + 64 + lane]; s1 = psum[row + 64 + lane]; }
      float m = fmaxf(m0, m1);
      #pragma unroll
      for (int d = 1; d < 64; d <<= 1) m = fmaxf(m, __shfl_xor(m, d));
      float s = s0 * __expf(m0 - m) + s1 * __expf(m1 - m);
      #pragma unroll
      for (int d = 1; d < 64; d <<= 1) s += __shfl_xor(s, d);
      sl += m + __logf(s);           // identical on all lanes
    }
    if (lane == 0) sRed[1 + w] = sl;
  }
  __syncthreads();
  if (tid == 0) {
    float sl = sRed[1] + sRed[2] + sRed[3];
    atomicAdd(out, (sl - sRed[0]) * (1.0f / (float)B_SZ));
  }
}

extern "C" void kernel_launch(void* const* d_in, const int* in_sizes, int n_in,
                              void* d_out, int out_size, void* d_ws, size_t ws_size,
                              hipStream_t stream) {
  (void)in_sizes; (void)n_in; (void)out_size; (void)ws_size;
  const float* enc      = (const float*)d_in[0];   // [16][500][256]
  const int*   enc_lens = (const int*)d_in[1];     // [16]
  const int*   y        = (const int*)d_in[2];     // [16][50]
  const int*   y_lens   = (const int*)d_in[3];     // [16]
  const float* W        = (const float*)d_in[4];   // [5000][256]
  const float* bias     = (const float*)d_in[5];   // [5000]
  float* out = (float*)d_out;

  char* ws = (char*)d_ws;
  _Float16* ench = (_Float16*)(ws + 0);            // 4,096,000 B
  _Float16* wh   = (_Float16*)(ws + 4096000);      // 2,560,000 B
  float* pmax    = (float*)(ws + 6656000);         // 2,560,000 B
  float* psum    = (float*)(ws + 9216000);         // 2,560,000 B
  float* lgT     = (float*)(ws + 11776000);        // 16*51*512*4 = 1,671,168 B

  k_f2h2<<<3250, 256, 0, stream>>>(enc, W, ench, wh, out);
  k_gemm_lse<<<dim3(40, 63), 256, 0, stream>>>(ench, wh, bias, y, pmax, psum, lgT);
  k_dp<<<16, 256, 0, stream>>>(lgT, pmax, psum, enc_lens, y, y_lens, out);
}